// Round 16
// baseline (271.520 us; speedup 1.0000x reference)
//
#include <hip/hip_runtime.h>

typedef __attribute__((ext_vector_type(8))) short bf16x8;
typedef __attribute__((ext_vector_type(4))) float f32x4;
typedef __attribute__((ext_vector_type(4))) unsigned short us4;
typedef __attribute__((ext_vector_type(4))) unsigned int u32x4;
typedef unsigned short us;

#define C2 0.18033688011112042f  /* SCALE * log2(e): Q pre-scale -> exp2-domain scores */

__device__ __forceinline__ unsigned short f2bf(float f) {
    unsigned int u = __float_as_uint(f);
    u = (u + 0x7FFF + ((u >> 16) & 1)) >> 16;   // RNE
    return (unsigned short)u;
}

// ---------------- prep kernels (merged dispatches; bodies proven) ----------

// blocks [0,4096): x fp32 -> bf16.  blocks [4096,12288): mask int32 -> bytes.
__global__ __launch_bounds__(256) void prep(const float* __restrict__ X,
                                            unsigned short* __restrict__ O,
                                            const int* __restrict__ Mi,
                                            unsigned int* __restrict__ Mo) {
    int bx = blockIdx.x;
    if (bx < 4096) {
        int i = bx * 256 + threadIdx.x;
        float4 v = ((const float4*)X)[i];
        us4 o;
        o.x = f2bf(v.x); o.y = f2bf(v.y); o.z = f2bf(v.z); o.w = f2bf(v.w);
        ((us4*)O)[i] = o;
    } else {
        int i = (bx - 4096) * 256 + threadIdx.x;
        int4 v = ((const int4*)Mi)[i];
        Mo[i] = (unsigned)(v.x & 1) | ((unsigned)(v.y & 1) << 8) |
                ((unsigned)(v.z & 1) << 16) | ((unsigned)(v.w & 1) << 24);
    }
}

// W [Kd][Cd] fp32 -> WT [Cd][Kd] bf16; two weight matrices in one launch.
__global__ __launch_bounds__(256) void transposew2(const float* __restrict__ W0,
                                                   unsigned short* __restrict__ WT0,
                                                   const float* __restrict__ W1,
                                                   unsigned short* __restrict__ WT1) {
    const float* W; unsigned short* WT; int Cd; int bx = blockIdx.x;
    if (bx < 96) { W = W0; WT = WT0; Cd = 3072; }
    else         { W = W1; WT = WT1; Cd = 1024; bx -= 96; }
    const int Kd = 1024;
    __shared__ float t[32][33];
    int c0 = bx * 32, k0 = blockIdx.y * 32;
    int tx = threadIdx.x & 31, ty = threadIdx.x >> 5;  // ty 0..7
#pragma unroll
    for (int i = 0; i < 32; i += 8)
        t[ty + i][tx] = W[(size_t)(k0 + ty + i) * Cd + c0 + tx];
    __syncthreads();
#pragma unroll
    for (int i = 0; i < 32; i += 8)
        WT[(size_t)(c0 + ty + i) * Kd + k0 + tx] = f2bf(t[tx][ty + i]);
}

// ---------------- GEMM: C = A[M][K] * BT[N][K]^T ----------------
// EXACT R10/R14 structure (proven pass pre+post). Serial stage via
// global_load_lds, explicit vmcnt drain + barrier, compute, barrier.
template <int MODE>
__global__ __launch_bounds__(256) void gemm_bf16(
    const unsigned short* __restrict__ A, const unsigned short* __restrict__ BT,
    int M, int N, int K,
    unsigned short* __restrict__ Qo, unsigned short* __restrict__ Ko,
    unsigned short* __restrict__ Vo,
    const float* __restrict__ bias, float* __restrict__ Co) {
    __shared__ unsigned short Asub[128 * 64];
    __shared__ unsigned short Bsub[128 * 64];
    const int bm = blockIdx.y, bn = blockIdx.x;
    const int tid = threadIdx.x, w = tid >> 6, lane = tid & 63;
    const int wr = w >> 1, wc = w & 1, l16 = lane & 15, lg = lane >> 4;

    f32x4 acc[4][4];
#pragma unroll
    for (int i = 0; i < 4; i++)
#pragma unroll
        for (int j = 0; j < 4; j++) acc[i][j] = (f32x4){0.f, 0.f, 0.f, 0.f};

    const int wbase = (tid & ~63) * 16;  // wave-uniform LDS offset

    const int nkt = K / 64;
    for (int kt = 0; kt < nkt; kt++) {
        const int k0 = kt * 64;
#pragma unroll
        for (int i = 0; i < 4; i++) {
            int slot = i * 256 + tid;
            int r = slot >> 3, blk = slot & 7;
            const us* srcA = A + (size_t)(bm * 128 + r) * K + k0 + ((blk ^ (r & 7)) << 3);
            __builtin_amdgcn_global_load_lds(
                (const __attribute__((address_space(1))) unsigned*)srcA,
                (__attribute__((address_space(3))) unsigned*)((char*)Asub + i * 4096 + wbase),
                16, 0, 0);
            const us* srcB = BT + (size_t)(bn * 128 + r) * K + k0 + ((blk ^ (r & 7)) << 3);
            __builtin_amdgcn_global_load_lds(
                (const __attribute__((address_space(1))) unsigned*)srcB,
                (__attribute__((address_space(3))) unsigned*)((char*)Bsub + i * 4096 + wbase),
                16, 0, 0);
        }
        asm volatile("s_waitcnt vmcnt(0)" ::: "memory");
        __builtin_amdgcn_sched_barrier(0);
        __syncthreads();
#pragma unroll
        for (int ks = 0; ks < 2; ks++) {
            bf16x8 af[4], bfr[4];
            int kk = ks * 32 + lg * 8;
#pragma unroll
            for (int i = 0; i < 4; i++) {
                int r = wr * 64 + i * 16 + l16;
                af[i] = *(bf16x8*)((char*)Asub + ((r * 128 + kk * 2) ^ ((r & 7) << 4)));
                int c = wc * 64 + i * 16 + l16;
                bfr[i] = *(bf16x8*)((char*)Bsub + ((c * 128 + kk * 2) ^ ((c & 7) << 4)));
            }
#pragma unroll
            for (int i = 0; i < 4; i++)
#pragma unroll
                for (int j = 0; j < 4; j++)
                    acc[i][j] = __builtin_amdgcn_mfma_f32_16x16x32_bf16(
                        af[i], bfr[j], acc[i][j], 0, 0, 0);
        }
        __syncthreads();
    }

    if (MODE == 0) {
#pragma unroll
        for (int i = 0; i < 4; i++) {
            int grow = bm * 128 + wr * 64 + i * 16 + lg * 4;
            int bb = grow >> 11, ll = grow & 2047;
#pragma unroll
            for (int j = 0; j < 4; j++) {
                int gcol = bn * 128 + wc * 64 + j * 16 + l16;
                int s = gcol >> 10, hh = (gcol >> 6) & 15, dd = gcol & 63;
                int bhh = bb * 16 + hh;
                if (s == 2) {
                    us4 pk;
                    pk.x = f2bf(acc[i][j][0]); pk.y = f2bf(acc[i][j][1]);
                    pk.z = f2bf(acc[i][j][2]); pk.w = f2bf(acc[i][j][3]);
                    *(us4*)(Vo + (size_t)(bhh * 64 + dd) * 2048 + ll) = pk;
                } else if (s == 0) {
                    // Q: pre-scale by C2 so QK^T lands in exp2 domain
                    unsigned short* dst = Qo + (size_t)(bhh * 2048 + ll) * 64 + dd;
#pragma unroll
                    for (int r = 0; r < 4; r++)
                        dst[(size_t)r * 64] = f2bf(acc[i][j][r] * C2);
                } else {
                    unsigned short* dst = Ko + (size_t)(bhh * 2048 + ll) * 64 + dd;
#pragma unroll
                    for (int r = 0; r < 4; r++) dst[(size_t)r * 64] = f2bf(acc[i][j][r]);
                }
            }
        }
    } else {
#pragma unroll
        for (int i = 0; i < 4; i++) {
            int grow = bm * 128 + wr * 64 + i * 16 + lg * 4;
#pragma unroll
            for (int j = 0; j < 4; j++) {
                int gcol = bn * 128 + wc * 64 + j * 16 + l16;
                float bv = bias[gcol];
#pragma unroll
                for (int r = 0; r < 4; r++)
                    Co[(size_t)(grow + r) * N + gcol] = acc[i][j][r] + bv;
            }
        }
    }
}

// ---------------- flash attention (LDS-staged K, direct-global V + mask) ----
// R15 body with ONE change: V is no longer LDS-staged. vf loaded directly
// from global VT (R5/R6-proven addressing), issued BEFORE QK^T and consumed
// after softmax (~400+cy later; L2-resident: 256KB/head). Halves stage bytes
// (16->8 KB/iter) -> shorter vmcnt drain; removes 8 ds_reads/wave/iter and
// their conflicts; LDS drops to 2x8KB. (m169 lesson: don't stage L2-fit data.)
__global__ __launch_bounds__(256, 4) void flash_attn(
    const us* __restrict__ Q, const us* __restrict__ Kt,
    const us* __restrict__ VT, const unsigned char* __restrict__ M8,
    us* __restrict__ Z) {
    __shared__ char lds[2][8192];   // per buf: K tile only
    const int bh = blockIdx.y;
    const int b = bh >> 4, h = bh & 15;
    const int tid = threadIdx.x, w = tid >> 6, lane = tid & 63;
    const int l16 = lane & 15, lg = lane >> 4;
    const int qb0 = blockIdx.x * 64;
    const int qrow = qb0 + w * 16 + l16;

    const size_t kbh = (size_t)bh * 2048;
    const size_t vbh = (size_t)bh * 64;

    const us* Qp = Q + (size_t)(kbh + qrow) * 64 + lg * 8;
    bf16x8 qf0 = *(const bf16x8*)(Qp);
    bf16x8 qf1 = *(const bf16x8*)(Qp + 32);

    float m_r = -__builtin_inff();
    float l_r = 0.f;
    f32x4 oacc[4];
#pragma unroll
    for (int jd = 0; jd < 4; jd++) oacc[jd] = (f32x4){0.f, 0.f, 0.f, 0.f};

    // exchange source lanes (loop-invariant)
    const int L0 = l16 + (((2 * lg) & 3) << 4);
    const int L1 = l16 + (((2 * lg + 1) & 3) << 4);
    const bool hi = (lg >> 1) != 0;

    // loop-invariant LDS read offsets (swizzled)
    int koff[8];
#pragma unroll
    for (int j = 0; j < 4; j++)
#pragma unroll
        for (int hh = 0; hh < 2; hh++)
            koff[2 * j + hh] = (16 * j + l16) * 128 + ((64 * hh + 16 * lg) ^ ((l16 & 7) << 4));

    // this lane's q-row mask bytes; per (kt,j): 4 consecutive keys 16j+4lg+r
    const unsigned char* mrow = M8 + (size_t)(b * 2048 + qrow) * 2048 + 4 * lg;
    // this lane's V fragment base: row jd*16+l16, col offset ks*32+lg*8
    const us* vrow = VT + (size_t)(vbh + l16) * 2048 + lg * 8;

    const int wbase = (tid & ~63) * 16;  // wave-uniform LDS offset (w*1024)

    auto STAGE = [&](int bufi, int kt) {
        char* base = &lds[bufi][0];
        const int lk = kt * 64;
#pragma unroll
        for (int i = 0; i < 2; i++) {
            int slot = i * 256 + tid;
            int r = slot >> 3, blk = slot & 7;
            const us* src = Kt + (kbh + lk + r) * 64 + ((blk ^ (r & 7)) << 3);
            __builtin_amdgcn_global_load_lds(
                (const __attribute__((address_space(1))) unsigned*)src,
                (__attribute__((address_space(3))) unsigned*)(base + i * 4096 + wbase),
                16, 0, 0);
        }
    };

    STAGE(0, 0);
    asm volatile("s_waitcnt vmcnt(0) lgkmcnt(0)" ::: "memory");
    __builtin_amdgcn_sched_barrier(0);
    __syncthreads();
    int cur = 0;

    for (int kt = 0; kt < 32; kt++) {
        const int lk0 = kt * 64;
        if (kt < 31) STAGE(cur ^ 1, kt + 1);   // issue next K tile; drained at barrier below
        // ---- mask bytes + V fragments for this iter: direct global (L2-hit,
        //      hidden under QK^T + softmax below) ----
        uchar4 mu[4];
#pragma unroll
        for (int j = 0; j < 4; j++)
            mu[j] = *(const uchar4*)(mrow + lk0 + 16 * j);
        bf16x8 vf[8];
#pragma unroll
        for (int ks = 0; ks < 2; ks++)
#pragma unroll
            for (int jd = 0; jd < 4; jd++)
                vf[ks * 4 + jd] =
                    *(const bf16x8*)(vrow + (size_t)(jd * 16) * 2048 + lk0 + ks * 32);
        char* Lb = &lds[cur][0];
        // ---- K fragments + QK^T (scores already exp2-domain) ----
        bf16x8 kf[8];
#pragma unroll
        for (int q8 = 0; q8 < 8; q8++) kf[q8] = *(const bf16x8*)(Lb + koff[q8]);
        f32x4 sacc[4];
#pragma unroll
        for (int j = 0; j < 4; j++) sacc[j] = (f32x4){0.f, 0.f, 0.f, 0.f};
#pragma unroll
        for (int j = 0; j < 4; j++) {
            sacc[j] = __builtin_amdgcn_mfma_f32_16x16x32_bf16(kf[2 * j], qf0, sacc[j], 0, 0, 0);
            sacc[j] = __builtin_amdgcn_mfma_f32_16x16x32_bf16(kf[2 * j + 1], qf1, sacc[j], 0, 0, 0);
        }
        // ---- tile max (in-lane over 16 keys, then across lg groups) ----
        float mx0 = fmaxf(fmaxf(sacc[0][0], sacc[0][1]), fmaxf(sacc[0][2], sacc[0][3]));
        float mx1 = fmaxf(fmaxf(sacc[1][0], sacc[1][1]), fmaxf(sacc[1][2], sacc[1][3]));
        float mx2 = fmaxf(fmaxf(sacc[2][0], sacc[2][1]), fmaxf(sacc[2][2], sacc[2][3]));
        float mx3 = fmaxf(fmaxf(sacc[3][0], sacc[3][1]), fmaxf(sacc[3][2], sacc[3][3]));
        float mx = fmaxf(fmaxf(mx0, mx1), fmaxf(mx2, mx3));
        mx = fmaxf(mx, __shfl_xor(mx, 16));
        mx = fmaxf(mx, __shfl_xor(mx, 32));
        // ---- defer-max: rescale only when tile max grows by >8 (uniform) ----
        if (mx > m_r + 8.f) {
            float alpha = __builtin_amdgcn_exp2f(m_r - mx);
            m_r = mx;
            l_r *= alpha;
#pragma unroll
            for (int jd = 0; jd < 4; jd++) {
                oacc[jd][0] *= alpha; oacc[jd][1] *= alpha;
                oacc[jd][2] *= alpha; oacc[jd][3] *= alpha;
            }
        }
        // ---- p = exp2(s - m_r) * mask; pack pairs via v_perm ----
        unsigned W[4][2];
        float rs = 0.f;
#pragma unroll
        for (int j = 0; j < 4; j++) {
            float p0 = __builtin_amdgcn_exp2f(sacc[j][0] - m_r) * (float)mu[j].x;
            float p1 = __builtin_amdgcn_exp2f(sacc[j][1] - m_r) * (float)mu[j].y;
            float p2 = __builtin_amdgcn_exp2f(sacc[j][2] - m_r) * (float)mu[j].z;
            float p3 = __builtin_amdgcn_exp2f(sacc[j][3] - m_r) * (float)mu[j].w;
            rs += (p0 + p1) + (p2 + p3);
            W[j][0] = __builtin_amdgcn_perm(__float_as_uint(p1), __float_as_uint(p0),
                                            0x07060302u);
            W[j][1] = __builtin_amdgcn_perm(__float_as_uint(p3), __float_as_uint(p2),
                                            0x07060302u);
        }
        rs += __shfl_xor(rs, 16);
        rs += __shfl_xor(rs, 32);
        l_r += rs;
        // ---- register-only P exchange + PV (vf loaded early from global) ----
#pragma unroll
        for (int ks = 0; ks < 2; ks++) {
            unsigned a0 = __shfl((int)W[2 * ks][0], L0), b0 = __shfl((int)W[2 * ks + 1][0], L0);
            unsigned a1 = __shfl((int)W[2 * ks][1], L0), b1 = __shfl((int)W[2 * ks + 1][1], L0);
            unsigned a2 = __shfl((int)W[2 * ks][0], L1), b2 = __shfl((int)W[2 * ks + 1][0], L1);
            unsigned a3 = __shfl((int)W[2 * ks][1], L1), b3 = __shfl((int)W[2 * ks + 1][1], L1);
            u32x4 pw = (u32x4){hi ? b0 : a0, hi ? b1 : a1, hi ? b2 : a2, hi ? b3 : a3};
            bf16x8 pB = __builtin_bit_cast(bf16x8, pw);
#pragma unroll
            for (int jd = 0; jd < 4; jd++)
                oacc[jd] = __builtin_amdgcn_mfma_f32_16x16x32_bf16(vf[ks * 4 + jd], pB,
                                                                   oacc[jd], 0, 0, 0);
        }
        // explicit drain: stage(kt+1) landed + all LDS reads complete, THEN barrier
        asm volatile("s_waitcnt vmcnt(0) lgkmcnt(0)" ::: "memory");
        __builtin_amdgcn_sched_barrier(0);
        __syncthreads();
        cur ^= 1;
    }

    const float inv = 1.0f / (l_r + 1e-20f);
    us* zp = Z + (size_t)(b * 2048 + qrow) * 1024 + h * 64 + lg * 4;
#pragma unroll
    for (int jd = 0; jd < 4; jd++) {
        us4 pk;
        pk.x = f2bf(oacc[jd][0] * inv);
        pk.y = f2bf(oacc[jd][1] * inv);
        pk.z = f2bf(oacc[jd][2] * inv);
        pk.w = f2bf(oacc[jd][3] * inv);
        *(us4*)(zp + jd * 16) = pk;
    }
}

// ---------------- launcher ----------------

extern "C" void kernel_launch(void* const* d_in, const int* in_sizes, int n_in,
                              void* d_out, int out_size, void* d_ws, size_t ws_size,
                              hipStream_t stream) {
    const float* x = (const float*)d_in[0];
    const int* mask = (const int*)d_in[1];
    const float* Wqkv = (const float*)d_in[2];
    const float* Wout = (const float*)d_in[3];
    const float* bout = (const float*)d_in[4];
    float* out = (float*)d_out;
    char* ws = (char*)d_ws;

    // 48 MB layout (proven)
    unsigned short* xz    = (unsigned short*)(ws);               // 8 MB (x bf16, later Z bf16)
    unsigned short* wqkvT = (unsigned short*)(ws + (8u << 20));  // 6 MB
    unsigned short* woutT = (unsigned short*)(ws + (14u << 20)); // 2 MB
    unsigned char*  m8    = (unsigned char*)(ws + (16u << 20));  // 8 MB
    unsigned short* Qb    = (unsigned short*)(ws + (24u << 20)); // 8 MB
    unsigned short* Kb    = (unsigned short*)(ws + (32u << 20)); // 8 MB
    unsigned short* VTb   = (unsigned short*)(ws + (40u << 20)); // 8 MB

    prep<<<12288, 256, 0, stream>>>(x, xz, mask, (unsigned int*)m8);
    transposew2<<<dim3(128, 32), 256, 0, stream>>>(Wqkv, wqkvT, Wout, woutT);
    gemm_bf16<0><<<dim3(3072 / 128, 4096 / 128), 256, 0, stream>>>(
        xz, wqkvT, 4096, 3072, 1024, Qb, Kb, VTb, nullptr, nullptr);
    flash_attn<<<dim3(32, 32), 256, 0, stream>>>(Qb, Kb, VTb, m8, xz);
    gemm_bf16<1><<<dim3(1024 / 128, 4096 / 128), 256, 0, stream>>>(
        xz, woutT, 4096, 1024, 1024, nullptr, nullptr, nullptr, bout, out);
}

// Round 17
// 171.543 us; speedup vs baseline: 1.5828x; 1.5828x over previous
//
#include <hip/hip_runtime.h>

typedef __attribute__((ext_vector_type(8))) short bf16x8;
typedef __attribute__((ext_vector_type(4))) float f32x4;
typedef __attribute__((ext_vector_type(4))) unsigned short us4;
typedef __attribute__((ext_vector_type(4))) unsigned int u32x4;
typedef unsigned short us;

#define C2 0.18033688011112042f  /* SCALE * log2(e): Q pre-scale -> exp2-domain scores */

__device__ __forceinline__ unsigned short f2bf(float f) {
    unsigned int u = __float_as_uint(f);
    u = (u + 0x7FFF + ((u >> 16) & 1)) >> 16;   // RNE
    return (unsigned short)u;
}

// ---------------- prep kernels (merged dispatches; bodies proven) ----------

// blocks [0,4096): x fp32 -> bf16.  blocks [4096,12288): mask int32 -> bytes.
__global__ __launch_bounds__(256) void prep(const float* __restrict__ X,
                                            unsigned short* __restrict__ O,
                                            const int* __restrict__ Mi,
                                            unsigned int* __restrict__ Mo) {
    int bx = blockIdx.x;
    if (bx < 4096) {
        int i = bx * 256 + threadIdx.x;
        float4 v = ((const float4*)X)[i];
        us4 o;
        o.x = f2bf(v.x); o.y = f2bf(v.y); o.z = f2bf(v.z); o.w = f2bf(v.w);
        ((us4*)O)[i] = o;
    } else {
        int i = (bx - 4096) * 256 + threadIdx.x;
        int4 v = ((const int4*)Mi)[i];
        Mo[i] = (unsigned)(v.x & 1) | ((unsigned)(v.y & 1) << 8) |
                ((unsigned)(v.z & 1) << 16) | ((unsigned)(v.w & 1) << 24);
    }
}

// W [Kd][Cd] fp32 -> WT [Cd][Kd] bf16; two weight matrices in one launch.
__global__ __launch_bounds__(256) void transposew2(const float* __restrict__ W0,
                                                   unsigned short* __restrict__ WT0,
                                                   const float* __restrict__ W1,
                                                   unsigned short* __restrict__ WT1) {
    const float* W; unsigned short* WT; int Cd; int bx = blockIdx.x;
    if (bx < 96) { W = W0; WT = WT0; Cd = 3072; }
    else         { W = W1; WT = WT1; Cd = 1024; bx -= 96; }
    const int Kd = 1024;
    __shared__ float t[32][33];
    int c0 = bx * 32, k0 = blockIdx.y * 32;
    int tx = threadIdx.x & 31, ty = threadIdx.x >> 5;  // ty 0..7
#pragma unroll
    for (int i = 0; i < 32; i += 8)
        t[ty + i][tx] = W[(size_t)(k0 + ty + i) * Cd + c0 + tx];
    __syncthreads();
#pragma unroll
    for (int i = 0; i < 32; i += 8)
        WT[(size_t)(c0 + ty + i) * Kd + k0 + tx] = f2bf(t[tx][ty + i]);
}

// ---------------- GEMM: C = A[M][K] * BT[N][K]^T ----------------
// EXACT R10/R14 structure (proven pass pre+post) + T1 XCD-aware block
// swizzle (pure bijective index remap; grids 768 and 256 are both %8==0):
// each XCD gets a contiguous chunk of the grid -> neighbor tiles share
// A-panel/B in its private L2 (m192: +10% when HBM/L2-bound).
template <int MODE>
__global__ __launch_bounds__(256) void gemm_bf16(
    const unsigned short* __restrict__ A, const unsigned short* __restrict__ BT,
    int M, int N, int K,
    unsigned short* __restrict__ Qo, unsigned short* __restrict__ Ko,
    unsigned short* __restrict__ Vo,
    const float* __restrict__ bias, float* __restrict__ Co) {
    __shared__ unsigned short Asub[128 * 64];
    __shared__ unsigned short Bsub[128 * 64];
    // XCD swizzle: lin = q*8+r -> swz = r*(nwg/8)+q  (bijective when nwg%8==0)
    const int nwg = gridDim.x * gridDim.y;
    const int lin = blockIdx.y * gridDim.x + blockIdx.x;
    const int swz = (lin & 7) * (nwg >> 3) + (lin >> 3);
    const int bm = swz / gridDim.x, bn = swz % gridDim.x;
    const int tid = threadIdx.x, w = tid >> 6, lane = tid & 63;
    const int wr = w >> 1, wc = w & 1, l16 = lane & 15, lg = lane >> 4;

    f32x4 acc[4][4];
#pragma unroll
    for (int i = 0; i < 4; i++)
#pragma unroll
        for (int j = 0; j < 4; j++) acc[i][j] = (f32x4){0.f, 0.f, 0.f, 0.f};

    const int wbase = (tid & ~63) * 16;  // wave-uniform LDS offset

    const int nkt = K / 64;
    for (int kt = 0; kt < nkt; kt++) {
        const int k0 = kt * 64;
#pragma unroll
        for (int i = 0; i < 4; i++) {
            int slot = i * 256 + tid;
            int r = slot >> 3, blk = slot & 7;
            const us* srcA = A + (size_t)(bm * 128 + r) * K + k0 + ((blk ^ (r & 7)) << 3);
            __builtin_amdgcn_global_load_lds(
                (const __attribute__((address_space(1))) unsigned*)srcA,
                (__attribute__((address_space(3))) unsigned*)((char*)Asub + i * 4096 + wbase),
                16, 0, 0);
            const us* srcB = BT + (size_t)(bn * 128 + r) * K + k0 + ((blk ^ (r & 7)) << 3);
            __builtin_amdgcn_global_load_lds(
                (const __attribute__((address_space(1))) unsigned*)srcB,
                (__attribute__((address_space(3))) unsigned*)((char*)Bsub + i * 4096 + wbase),
                16, 0, 0);
        }
        asm volatile("s_waitcnt vmcnt(0)" ::: "memory");
        __builtin_amdgcn_sched_barrier(0);
        __syncthreads();
#pragma unroll
        for (int ks = 0; ks < 2; ks++) {
            bf16x8 af[4], bfr[4];
            int kk = ks * 32 + lg * 8;
#pragma unroll
            for (int i = 0; i < 4; i++) {
                int r = wr * 64 + i * 16 + l16;
                af[i] = *(bf16x8*)((char*)Asub + ((r * 128 + kk * 2) ^ ((r & 7) << 4)));
                int c = wc * 64 + i * 16 + l16;
                bfr[i] = *(bf16x8*)((char*)Bsub + ((c * 128 + kk * 2) ^ ((c & 7) << 4)));
            }
#pragma unroll
            for (int i = 0; i < 4; i++)
#pragma unroll
                for (int j = 0; j < 4; j++)
                    acc[i][j] = __builtin_amdgcn_mfma_f32_16x16x32_bf16(
                        af[i], bfr[j], acc[i][j], 0, 0, 0);
        }
        __syncthreads();
    }

    if (MODE == 0) {
#pragma unroll
        for (int i = 0; i < 4; i++) {
            int grow = bm * 128 + wr * 64 + i * 16 + lg * 4;
            int bb = grow >> 11, ll = grow & 2047;
#pragma unroll
            for (int j = 0; j < 4; j++) {
                int gcol = bn * 128 + wc * 64 + j * 16 + l16;
                int s = gcol >> 10, hh = (gcol >> 6) & 15, dd = gcol & 63;
                int bhh = bb * 16 + hh;
                if (s == 2) {
                    us4 pk;
                    pk.x = f2bf(acc[i][j][0]); pk.y = f2bf(acc[i][j][1]);
                    pk.z = f2bf(acc[i][j][2]); pk.w = f2bf(acc[i][j][3]);
                    *(us4*)(Vo + (size_t)(bhh * 64 + dd) * 2048 + ll) = pk;
                } else if (s == 0) {
                    // Q: pre-scale by C2 so QK^T lands in exp2 domain
                    unsigned short* dst = Qo + (size_t)(bhh * 2048 + ll) * 64 + dd;
#pragma unroll
                    for (int r = 0; r < 4; r++)
                        dst[(size_t)r * 64] = f2bf(acc[i][j][r] * C2);
                } else {
                    unsigned short* dst = Ko + (size_t)(bhh * 2048 + ll) * 64 + dd;
#pragma unroll
                    for (int r = 0; r < 4; r++) dst[(size_t)r * 64] = f2bf(acc[i][j][r]);
                }
            }
        }
    } else {
#pragma unroll
        for (int i = 0; i < 4; i++) {
            int grow = bm * 128 + wr * 64 + i * 16 + lg * 4;
#pragma unroll
            for (int j = 0; j < 4; j++) {
                int gcol = bn * 128 + wc * 64 + j * 16 + l16;
                float bv = bias[gcol];
#pragma unroll
                for (int r = 0; r < 4; r++)
                    Co[(size_t)(grow + r) * N + gcol] = acc[i][j][r] + bv;
            }
        }
    }
}

// ---------------- flash attention (LDS-staged K/V, direct-global mask) ------
// EXACT R15 body (passed pre+post; 93 us). R16's direct-global V regressed
// 2x: compiler sinks plain per-lane global loads to their use (VGPR 56),
// serializing 8 L2 latencies per iter — LDS staging is the only proven
// latency-hider in this register regime.
__global__ __launch_bounds__(256, 5) void flash_attn(
    const us* __restrict__ Q, const us* __restrict__ Kt,
    const us* __restrict__ VT, const unsigned char* __restrict__ M8,
    us* __restrict__ Z) {
    __shared__ char lds[2][16384];   // per buf: K 0..8191, VT 8192..16383
    const int bh = blockIdx.y;
    const int b = bh >> 4, h = bh & 15;
    const int tid = threadIdx.x, w = tid >> 6, lane = tid & 63;
    const int l16 = lane & 15, lg = lane >> 4;
    const int qb0 = blockIdx.x * 64;
    const int qrow = qb0 + w * 16 + l16;

    const size_t kbh = (size_t)bh * 2048;
    const size_t vbh = (size_t)bh * 64;

    const us* Qp = Q + (size_t)(kbh + qrow) * 64 + lg * 8;
    bf16x8 qf0 = *(const bf16x8*)(Qp);
    bf16x8 qf1 = *(const bf16x8*)(Qp + 32);

    float m_r = -__builtin_inff();
    float l_r = 0.f;
    f32x4 oacc[4];
#pragma unroll
    for (int jd = 0; jd < 4; jd++) oacc[jd] = (f32x4){0.f, 0.f, 0.f, 0.f};

    // exchange source lanes (loop-invariant)
    const int L0 = l16 + (((2 * lg) & 3) << 4);
    const int L1 = l16 + (((2 * lg + 1) & 3) << 4);
    const bool hi = (lg >> 1) != 0;

    // loop-invariant LDS read offsets (swizzled)
    int koff[8], voff[8];
#pragma unroll
    for (int j = 0; j < 4; j++)
#pragma unroll
        for (int hh = 0; hh < 2; hh++)
            koff[2 * j + hh] = (16 * j + l16) * 128 + ((64 * hh + 16 * lg) ^ ((l16 & 7) << 4));
#pragma unroll
    for (int ks = 0; ks < 2; ks++)
#pragma unroll
        for (int jd = 0; jd < 4; jd++)
            voff[ks * 4 + jd] =
                8192 + (jd * 16 + l16) * 128 + ((64 * ks + 16 * lg) ^ ((l16 & 7) << 4));

    // this lane's q-row mask bytes; per (kt,j): 4 consecutive keys 16j+4lg+r
    const unsigned char* mrow = M8 + (size_t)(b * 2048 + qrow) * 2048 + 4 * lg;

    const int wbase = (tid & ~63) * 16;  // wave-uniform LDS offset (w*1024)

    auto STAGE = [&](int bufi, int kt) {
        char* base = &lds[bufi][0];
        const int lk = kt * 64;
#pragma unroll
        for (int i = 0; i < 2; i++) {
            int slot = i * 256 + tid;
            int r = slot >> 3, blk = slot & 7;
            const us* src = Kt + (kbh + lk + r) * 64 + ((blk ^ (r & 7)) << 3);
            __builtin_amdgcn_global_load_lds(
                (const __attribute__((address_space(1))) unsigned*)src,
                (__attribute__((address_space(3))) unsigned*)(base + i * 4096 + wbase),
                16, 0, 0);
        }
#pragma unroll
        for (int i = 0; i < 2; i++) {
            int slot = i * 256 + tid;
            int r = slot >> 3, blk = slot & 7;
            const us* src = VT + (vbh + r) * 2048 + lk + ((blk ^ (r & 7)) << 3);
            __builtin_amdgcn_global_load_lds(
                (const __attribute__((address_space(1))) unsigned*)src,
                (__attribute__((address_space(3))) unsigned*)(base + 8192 + i * 4096 + wbase),
                16, 0, 0);
        }
    };

    STAGE(0, 0);
    asm volatile("s_waitcnt vmcnt(0) lgkmcnt(0)" ::: "memory");
    __builtin_amdgcn_sched_barrier(0);
    __syncthreads();
    int cur = 0;

    for (int kt = 0; kt < 32; kt++) {
        const int lk0 = kt * 64;
        if (kt < 31) STAGE(cur ^ 1, kt + 1);   // issue next tile; drained at barrier below
        // ---- mask bytes for this iter: direct global (L2-hit ~200cy, hidden
        //      under QK^T + max below) ----
        uchar4 mu[4];
#pragma unroll
        for (int j = 0; j < 4; j++)
            mu[j] = *(const uchar4*)(mrow + lk0 + 16 * j);
        char* Lb = &lds[cur][0];
        // ---- K fragments + QK^T (scores already exp2-domain) ----
        bf16x8 kf[8];
#pragma unroll
        for (int q8 = 0; q8 < 8; q8++) kf[q8] = *(const bf16x8*)(Lb + koff[q8]);
        f32x4 sacc[4];
#pragma unroll
        for (int j = 0; j < 4; j++) sacc[j] = (f32x4){0.f, 0.f, 0.f, 0.f};
#pragma unroll
        for (int j = 0; j < 4; j++) {
            sacc[j] = __builtin_amdgcn_mfma_f32_16x16x32_bf16(kf[2 * j], qf0, sacc[j], 0, 0, 0);
            sacc[j] = __builtin_amdgcn_mfma_f32_16x16x32_bf16(kf[2 * j + 1], qf1, sacc[j], 0, 0, 0);
        }
        // ---- tile max (in-lane over 16 keys, then across lg groups) ----
        float mx0 = fmaxf(fmaxf(sacc[0][0], sacc[0][1]), fmaxf(sacc[0][2], sacc[0][3]));
        float mx1 = fmaxf(fmaxf(sacc[1][0], sacc[1][1]), fmaxf(sacc[1][2], sacc[1][3]));
        float mx2 = fmaxf(fmaxf(sacc[2][0], sacc[2][1]), fmaxf(sacc[2][2], sacc[2][3]));
        float mx3 = fmaxf(fmaxf(sacc[3][0], sacc[3][1]), fmaxf(sacc[3][2], sacc[3][3]));
        float mx = fmaxf(fmaxf(mx0, mx1), fmaxf(mx2, mx3));
        mx = fmaxf(mx, __shfl_xor(mx, 16));
        mx = fmaxf(mx, __shfl_xor(mx, 32));
        // ---- defer-max: rescale only when tile max grows by >8 (uniform) ----
        if (mx > m_r + 8.f) {
            float alpha = __builtin_amdgcn_exp2f(m_r - mx);
            m_r = mx;
            l_r *= alpha;
#pragma unroll
            for (int jd = 0; jd < 4; jd++) {
                oacc[jd][0] *= alpha; oacc[jd][1] *= alpha;
                oacc[jd][2] *= alpha; oacc[jd][3] *= alpha;
            }
        }
        // ---- p = exp2(s - m_r) * mask; pack pairs via v_perm ----
        unsigned W[4][2];
        float rs = 0.f;
#pragma unroll
        for (int j = 0; j < 4; j++) {
            float p0 = __builtin_amdgcn_exp2f(sacc[j][0] - m_r) * (float)mu[j].x;
            float p1 = __builtin_amdgcn_exp2f(sacc[j][1] - m_r) * (float)mu[j].y;
            float p2 = __builtin_amdgcn_exp2f(sacc[j][2] - m_r) * (float)mu[j].z;
            float p3 = __builtin_amdgcn_exp2f(sacc[j][3] - m_r) * (float)mu[j].w;
            rs += (p0 + p1) + (p2 + p3);
            W[j][0] = __builtin_amdgcn_perm(__float_as_uint(p1), __float_as_uint(p0),
                                            0x07060302u);
            W[j][1] = __builtin_amdgcn_perm(__float_as_uint(p3), __float_as_uint(p2),
                                            0x07060302u);
        }
        rs += __shfl_xor(rs, 16);
        rs += __shfl_xor(rs, 32);
        l_r += rs;
        // ---- register-only P exchange + PV (V frags per ks-half) ----
#pragma unroll
        for (int ks = 0; ks < 2; ks++) {
            bf16x8 vf[4];
#pragma unroll
            for (int jd = 0; jd < 4; jd++)
                vf[jd] = *(const bf16x8*)(Lb + voff[ks * 4 + jd]);
            unsigned a0 = __shfl((int)W[2 * ks][0], L0), b0 = __shfl((int)W[2 * ks + 1][0], L0);
            unsigned a1 = __shfl((int)W[2 * ks][1], L0), b1 = __shfl((int)W[2 * ks + 1][1], L0);
            unsigned a2 = __shfl((int)W[2 * ks][0], L1), b2 = __shfl((int)W[2 * ks + 1][0], L1);
            unsigned a3 = __shfl((int)W[2 * ks][1], L1), b3 = __shfl((int)W[2 * ks + 1][1], L1);
            u32x4 pw = (u32x4){hi ? b0 : a0, hi ? b1 : a1, hi ? b2 : a2, hi ? b3 : a3};
            bf16x8 pB = __builtin_bit_cast(bf16x8, pw);
#pragma unroll
            for (int jd = 0; jd < 4; jd++)
                oacc[jd] = __builtin_amdgcn_mfma_f32_16x16x32_bf16(vf[jd], pB,
                                                                   oacc[jd], 0, 0, 0);
        }
        // explicit drain: stage(kt+1) landed + all LDS reads complete, THEN barrier
        asm volatile("s_waitcnt vmcnt(0) lgkmcnt(0)" ::: "memory");
        __builtin_amdgcn_sched_barrier(0);
        __syncthreads();
        cur ^= 1;
    }

    const float inv = 1.0f / (l_r + 1e-20f);
    us* zp = Z + (size_t)(b * 2048 + qrow) * 1024 + h * 64 + lg * 4;
#pragma unroll
    for (int jd = 0; jd < 4; jd++) {
        us4 pk;
        pk.x = f2bf(oacc[jd][0] * inv);
        pk.y = f2bf(oacc[jd][1] * inv);
        pk.z = f2bf(oacc[jd][2] * inv);
        pk.w = f2bf(oacc[jd][3] * inv);
        *(us4*)(zp + jd * 16) = pk;
    }
}

// ---------------- launcher ----------------

extern "C" void kernel_launch(void* const* d_in, const int* in_sizes, int n_in,
                              void* d_out, int out_size, void* d_ws, size_t ws_size,
                              hipStream_t stream) {
    const float* x = (const float*)d_in[0];
    const int* mask = (const int*)d_in[1];
    const float* Wqkv = (const float*)d_in[2];
    const float* Wout = (const float*)d_in[3];
    const float* bout = (const float*)d_in[4];
    float* out = (float*)d_out;
    char* ws = (char*)d_ws;

    // 48 MB layout (proven)
    unsigned short* xz    = (unsigned short*)(ws);               // 8 MB (x bf16, later Z bf16)
    unsigned short* wqkvT = (unsigned short*)(ws + (8u << 20));  // 6 MB
    unsigned short* woutT = (unsigned short*)(ws + (14u << 20)); // 2 MB
    unsigned char*  m8    = (unsigned char*)(ws + (16u << 20));  // 8 MB
    unsigned short* Qb    = (unsigned short*)(ws + (24u << 20)); // 8 MB
    unsigned short* Kb    = (unsigned short*)(ws + (32u << 20)); // 8 MB
    unsigned short* VTb   = (unsigned short*)(ws + (40u << 20)); // 8 MB

    prep<<<12288, 256, 0, stream>>>(x, xz, mask, (unsigned int*)m8);
    transposew2<<<dim3(128, 32), 256, 0, stream>>>(Wqkv, wqkvT, Wout, woutT);
    gemm_bf16<0><<<dim3(3072 / 128, 4096 / 128), 256, 0, stream>>>(
        xz, wqkvT, 4096, 3072, 1024, Qb, Kb, VTb, nullptr, nullptr);
    flash_attn<<<dim3(32, 32), 256, 0, stream>>>(Qb, Kb, VTb, m8, xz);
    gemm_bf16<1><<<dim3(1024 / 128, 4096 / 128), 256, 0, stream>>>(
        xz, woutT, 4096, 1024, 1024, nullptr, nullptr, nullptr, bout, out);
}

// Round 18
// 159.261 us; speedup vs baseline: 1.7049x; 1.0771x over previous
//
#include <hip/hip_runtime.h>

typedef __attribute__((ext_vector_type(8))) short bf16x8;
typedef __attribute__((ext_vector_type(4))) float f32x4;
typedef __attribute__((ext_vector_type(4))) unsigned short us4;
typedef __attribute__((ext_vector_type(4))) unsigned int u32x4;
typedef unsigned short us;

#define C2 0.18033688011112042f  /* SCALE * log2(e): Q pre-scale -> exp2-domain scores */

__device__ __forceinline__ unsigned short f2bf(float f) {
    unsigned int u = __float_as_uint(f);
    u = (u + 0x7FFF + ((u >> 16) & 1)) >> 16;   // RNE
    return (unsigned short)u;
}

// ---------------- prep kernels (merged dispatches; bodies proven) ----------

// blocks [0,4096): x fp32 -> bf16.  blocks [4096,12288): mask int32 -> bytes.
__global__ __launch_bounds__(256) void prep(const float* __restrict__ X,
                                            unsigned short* __restrict__ O,
                                            const int* __restrict__ Mi,
                                            unsigned int* __restrict__ Mo) {
    int bx = blockIdx.x;
    if (bx < 4096) {
        int i = bx * 256 + threadIdx.x;
        float4 v = ((const float4*)X)[i];
        us4 o;
        o.x = f2bf(v.x); o.y = f2bf(v.y); o.z = f2bf(v.z); o.w = f2bf(v.w);
        ((us4*)O)[i] = o;
    } else {
        int i = (bx - 4096) * 256 + threadIdx.x;
        int4 v = ((const int4*)Mi)[i];
        Mo[i] = (unsigned)(v.x & 1) | ((unsigned)(v.y & 1) << 8) |
                ((unsigned)(v.z & 1) << 16) | ((unsigned)(v.w & 1) << 24);
    }
}

// W [Kd][Cd] fp32 -> WT [Cd][Kd] bf16; two weight matrices in one launch.
__global__ __launch_bounds__(256) void transposew2(const float* __restrict__ W0,
                                                   unsigned short* __restrict__ WT0,
                                                   const float* __restrict__ W1,
                                                   unsigned short* __restrict__ WT1) {
    const float* W; unsigned short* WT; int Cd; int bx = blockIdx.x;
    if (bx < 96) { W = W0; WT = WT0; Cd = 3072; }
    else         { W = W1; WT = WT1; Cd = 1024; bx -= 96; }
    const int Kd = 1024;
    __shared__ float t[32][33];
    int c0 = bx * 32, k0 = blockIdx.y * 32;
    int tx = threadIdx.x & 31, ty = threadIdx.x >> 5;  // ty 0..7
#pragma unroll
    for (int i = 0; i < 32; i += 8)
        t[ty + i][tx] = W[(size_t)(k0 + ty + i) * Cd + c0 + tx];
    __syncthreads();
#pragma unroll
    for (int i = 0; i < 32; i += 8)
        WT[(size_t)(c0 + ty + i) * Kd + k0 + tx] = f2bf(t[tx][ty + i]);
}

// ---------------- GEMM: C = A[M][K] * BT[N][K]^T ----------------
// EXACT R14/R15 structure (proven pass pre+post; swizzle reverted — R17
// showed it neutral-to-negative since all operands are L3-resident).
template <int MODE>
__global__ __launch_bounds__(256) void gemm_bf16(
    const unsigned short* __restrict__ A, const unsigned short* __restrict__ BT,
    int M, int N, int K,
    unsigned short* __restrict__ Qo, unsigned short* __restrict__ Ko,
    unsigned short* __restrict__ Vo,
    const float* __restrict__ bias, float* __restrict__ Co) {
    __shared__ unsigned short Asub[128 * 64];
    __shared__ unsigned short Bsub[128 * 64];
    const int bm = blockIdx.y, bn = blockIdx.x;
    const int tid = threadIdx.x, w = tid >> 6, lane = tid & 63;
    const int wr = w >> 1, wc = w & 1, l16 = lane & 15, lg = lane >> 4;

    f32x4 acc[4][4];
#pragma unroll
    for (int i = 0; i < 4; i++)
#pragma unroll
        for (int j = 0; j < 4; j++) acc[i][j] = (f32x4){0.f, 0.f, 0.f, 0.f};

    const int wbase = (tid & ~63) * 16;  // wave-uniform LDS offset

    const int nkt = K / 64;
    for (int kt = 0; kt < nkt; kt++) {
        const int k0 = kt * 64;
#pragma unroll
        for (int i = 0; i < 4; i++) {
            int slot = i * 256 + tid;
            int r = slot >> 3, blk = slot & 7;
            const us* srcA = A + (size_t)(bm * 128 + r) * K + k0 + ((blk ^ (r & 7)) << 3);
            __builtin_amdgcn_global_load_lds(
                (const __attribute__((address_space(1))) unsigned*)srcA,
                (__attribute__((address_space(3))) unsigned*)((char*)Asub + i * 4096 + wbase),
                16, 0, 0);
            const us* srcB = BT + (size_t)(bn * 128 + r) * K + k0 + ((blk ^ (r & 7)) << 3);
            __builtin_amdgcn_global_load_lds(
                (const __attribute__((address_space(1))) unsigned*)srcB,
                (__attribute__((address_space(3))) unsigned*)((char*)Bsub + i * 4096 + wbase),
                16, 0, 0);
        }
        asm volatile("s_waitcnt vmcnt(0)" ::: "memory");
        __builtin_amdgcn_sched_barrier(0);
        __syncthreads();
#pragma unroll
        for (int ks = 0; ks < 2; ks++) {
            bf16x8 af[4], bfr[4];
            int kk = ks * 32 + lg * 8;
#pragma unroll
            for (int i = 0; i < 4; i++) {
                int r = wr * 64 + i * 16 + l16;
                af[i] = *(bf16x8*)((char*)Asub + ((r * 128 + kk * 2) ^ ((r & 7) << 4)));
                int c = wc * 64 + i * 16 + l16;
                bfr[i] = *(bf16x8*)((char*)Bsub + ((c * 128 + kk * 2) ^ ((c & 7) << 4)));
            }
#pragma unroll
            for (int i = 0; i < 4; i++)
#pragma unroll
                for (int j = 0; j < 4; j++)
                    acc[i][j] = __builtin_amdgcn_mfma_f32_16x16x32_bf16(
                        af[i], bfr[j], acc[i][j], 0, 0, 0);
        }
        __syncthreads();
    }

    if (MODE == 0) {
#pragma unroll
        for (int i = 0; i < 4; i++) {
            int grow = bm * 128 + wr * 64 + i * 16 + lg * 4;
            int bb = grow >> 11, ll = grow & 2047;
#pragma unroll
            for (int j = 0; j < 4; j++) {
                int gcol = bn * 128 + wc * 64 + j * 16 + l16;
                int s = gcol >> 10, hh = (gcol >> 6) & 15, dd = gcol & 63;
                int bhh = bb * 16 + hh;
                if (s == 2) {
                    us4 pk;
                    pk.x = f2bf(acc[i][j][0]); pk.y = f2bf(acc[i][j][1]);
                    pk.z = f2bf(acc[i][j][2]); pk.w = f2bf(acc[i][j][3]);
                    *(us4*)(Vo + (size_t)(bhh * 64 + dd) * 2048 + ll) = pk;
                } else if (s == 0) {
                    // Q: pre-scale by C2 so QK^T lands in exp2 domain
                    unsigned short* dst = Qo + (size_t)(bhh * 2048 + ll) * 64 + dd;
#pragma unroll
                    for (int r = 0; r < 4; r++)
                        dst[(size_t)r * 64] = f2bf(acc[i][j][r] * C2);
                } else {
                    unsigned short* dst = Ko + (size_t)(bhh * 2048 + ll) * 64 + dd;
#pragma unroll
                    for (int r = 0; r < 4; r++) dst[(size_t)r * 64] = f2bf(acc[i][j][r]);
                }
            }
        }
    } else {
#pragma unroll
        for (int i = 0; i < 4; i++) {
            int grow = bm * 128 + wr * 64 + i * 16 + lg * 4;
#pragma unroll
            for (int j = 0; j < 4; j++) {
                int gcol = bn * 128 + wc * 64 + j * 16 + l16;
                float bv = bias[gcol];
#pragma unroll
                for (int r = 0; r < 4; r++)
                    Co[(size_t)(grow + r) * N + gcol] = acc[i][j][r] + bv;
            }
        }
    }
}

// ---------------- flash attention (LDS-staged K/V, 8-wave blocks) -----------
// R15 body, 4 -> 8 waves/block (512 thr, 128 q-rows, grid 16x32=512):
// per-CU resident waves unchanged (2 blocks x 8 = 16) but each staged K/V
// tile feeds 2x the q-rows -> per-CU stage traffic halves (64->32 KB/round),
// K/V L2 traffic halves. Sync structure byte-identical (parameter change
// inheriting the 5x-passed template). Per-wave math untouched.
__global__ __launch_bounds__(512, 4) void flash_attn(
    const us* __restrict__ Q, const us* __restrict__ Kt,
    const us* __restrict__ VT, const unsigned char* __restrict__ M8,
    us* __restrict__ Z) {
    __shared__ char lds[2][16384];   // per buf: K 0..8191, VT 8192..16383
    const int bh = blockIdx.y;
    const int b = bh >> 4, h = bh & 15;
    const int tid = threadIdx.x, w = tid >> 6, lane = tid & 63;
    const int l16 = lane & 15, lg = lane >> 4;
    const int qb0 = blockIdx.x * 128;
    const int qrow = qb0 + w * 16 + l16;

    const size_t kbh = (size_t)bh * 2048;
    const size_t vbh = (size_t)bh * 64;

    const us* Qp = Q + (size_t)(kbh + qrow) * 64 + lg * 8;
    bf16x8 qf0 = *(const bf16x8*)(Qp);
    bf16x8 qf1 = *(const bf16x8*)(Qp + 32);

    float m_r = -__builtin_inff();
    float l_r = 0.f;
    f32x4 oacc[4];
#pragma unroll
    for (int jd = 0; jd < 4; jd++) oacc[jd] = (f32x4){0.f, 0.f, 0.f, 0.f};

    // exchange source lanes (loop-invariant)
    const int L0 = l16 + (((2 * lg) & 3) << 4);
    const int L1 = l16 + (((2 * lg + 1) & 3) << 4);
    const bool hi = (lg >> 1) != 0;

    // loop-invariant LDS read offsets (swizzled)
    int koff[8], voff[8];
#pragma unroll
    for (int j = 0; j < 4; j++)
#pragma unroll
        for (int hh = 0; hh < 2; hh++)
            koff[2 * j + hh] = (16 * j + l16) * 128 + ((64 * hh + 16 * lg) ^ ((l16 & 7) << 4));
#pragma unroll
    for (int ks = 0; ks < 2; ks++)
#pragma unroll
        for (int jd = 0; jd < 4; jd++)
            voff[ks * 4 + jd] =
                8192 + (jd * 16 + l16) * 128 + ((64 * ks + 16 * lg) ^ ((l16 & 7) << 4));

    // this lane's q-row mask bytes; per (kt,j): 4 consecutive keys 16j+4lg+r
    const unsigned char* mrow = M8 + (size_t)(b * 2048 + qrow) * 2048 + 4 * lg;

    const int wbase = (tid & ~63) * 16;  // wave-uniform LDS offset (w*1024)

    // 512 threads: K tile = 512 slots (1/thread), V tile = 512 slots (1/thread)
    auto STAGE = [&](int bufi, int kt) {
        char* base = &lds[bufi][0];
        const int lk = kt * 64;
        {
            int r = tid >> 3, blk = tid & 7;
            const us* src = Kt + (kbh + lk + r) * 64 + ((blk ^ (r & 7)) << 3);
            __builtin_amdgcn_global_load_lds(
                (const __attribute__((address_space(1))) unsigned*)src,
                (__attribute__((address_space(3))) unsigned*)(base + wbase),
                16, 0, 0);
        }
        {
            int r = tid >> 3, blk = tid & 7;
            const us* src = VT + (vbh + r) * 2048 + lk + ((blk ^ (r & 7)) << 3);
            __builtin_amdgcn_global_load_lds(
                (const __attribute__((address_space(1))) unsigned*)src,
                (__attribute__((address_space(3))) unsigned*)(base + 8192 + wbase),
                16, 0, 0);
        }
    };

    STAGE(0, 0);
    asm volatile("s_waitcnt vmcnt(0) lgkmcnt(0)" ::: "memory");
    __builtin_amdgcn_sched_barrier(0);
    __syncthreads();
    int cur = 0;

    for (int kt = 0; kt < 32; kt++) {
        const int lk0 = kt * 64;
        if (kt < 31) STAGE(cur ^ 1, kt + 1);   // issue next tile; drained at barrier below
        // ---- mask bytes for this iter: direct global (hidden under QK^T) ----
        uchar4 mu[4];
#pragma unroll
        for (int j = 0; j < 4; j++)
            mu[j] = *(const uchar4*)(mrow + lk0 + 16 * j);
        char* Lb = &lds[cur][0];
        // ---- K fragments + QK^T (scores already exp2-domain) ----
        bf16x8 kf[8];
#pragma unroll
        for (int q8 = 0; q8 < 8; q8++) kf[q8] = *(const bf16x8*)(Lb + koff[q8]);
        f32x4 sacc[4];
#pragma unroll
        for (int j = 0; j < 4; j++) sacc[j] = (f32x4){0.f, 0.f, 0.f, 0.f};
#pragma unroll
        for (int j = 0; j < 4; j++) {
            sacc[j] = __builtin_amdgcn_mfma_f32_16x16x32_bf16(kf[2 * j], qf0, sacc[j], 0, 0, 0);
            sacc[j] = __builtin_amdgcn_mfma_f32_16x16x32_bf16(kf[2 * j + 1], qf1, sacc[j], 0, 0, 0);
        }
        // ---- tile max (in-lane over 16 keys, then across lg groups) ----
        float mx0 = fmaxf(fmaxf(sacc[0][0], sacc[0][1]), fmaxf(sacc[0][2], sacc[0][3]));
        float mx1 = fmaxf(fmaxf(sacc[1][0], sacc[1][1]), fmaxf(sacc[1][2], sacc[1][3]));
        float mx2 = fmaxf(fmaxf(sacc[2][0], sacc[2][1]), fmaxf(sacc[2][2], sacc[2][3]));
        float mx3 = fmaxf(fmaxf(sacc[3][0], sacc[3][1]), fmaxf(sacc[3][2], sacc[3][3]));
        float mx = fmaxf(fmaxf(mx0, mx1), fmaxf(mx2, mx3));
        mx = fmaxf(mx, __shfl_xor(mx, 16));
        mx = fmaxf(mx, __shfl_xor(mx, 32));
        // ---- defer-max: rescale only when tile max grows by >8 (uniform) ----
        if (mx > m_r + 8.f) {
            float alpha = __builtin_amdgcn_exp2f(m_r - mx);
            m_r = mx;
            l_r *= alpha;
#pragma unroll
            for (int jd = 0; jd < 4; jd++) {
                oacc[jd][0] *= alpha; oacc[jd][1] *= alpha;
                oacc[jd][2] *= alpha; oacc[jd][3] *= alpha;
            }
        }
        // ---- p = exp2(s - m_r) * mask; pack pairs via v_perm ----
        unsigned W[4][2];
        float rs = 0.f;
#pragma unroll
        for (int j = 0; j < 4; j++) {
            float p0 = __builtin_amdgcn_exp2f(sacc[j][0] - m_r) * (float)mu[j].x;
            float p1 = __builtin_amdgcn_exp2f(sacc[j][1] - m_r) * (float)mu[j].y;
            float p2 = __builtin_amdgcn_exp2f(sacc[j][2] - m_r) * (float)mu[j].z;
            float p3 = __builtin_amdgcn_exp2f(sacc[j][3] - m_r) * (float)mu[j].w;
            rs += (p0 + p1) + (p2 + p3);
            W[j][0] = __builtin_amdgcn_perm(__float_as_uint(p1), __float_as_uint(p0),
                                            0x07060302u);
            W[j][1] = __builtin_amdgcn_perm(__float_as_uint(p3), __float_as_uint(p2),
                                            0x07060302u);
        }
        rs += __shfl_xor(rs, 16);
        rs += __shfl_xor(rs, 32);
        l_r += rs;
        // ---- register-only P exchange + PV (V frags per ks-half) ----
#pragma unroll
        for (int ks = 0; ks < 2; ks++) {
            bf16x8 vf[4];
#pragma unroll
            for (int jd = 0; jd < 4; jd++)
                vf[jd] = *(const bf16x8*)(Lb + voff[ks * 4 + jd]);
            unsigned a0 = __shfl((int)W[2 * ks][0], L0), b0 = __shfl((int)W[2 * ks + 1][0], L0);
            unsigned a1 = __shfl((int)W[2 * ks][1], L0), b1 = __shfl((int)W[2 * ks + 1][1], L0);
            unsigned a2 = __shfl((int)W[2 * ks][0], L1), b2 = __shfl((int)W[2 * ks + 1][0], L1);
            unsigned a3 = __shfl((int)W[2 * ks][1], L1), b3 = __shfl((int)W[2 * ks + 1][1], L1);
            u32x4 pw = (u32x4){hi ? b0 : a0, hi ? b1 : a1, hi ? b2 : a2, hi ? b3 : a3};
            bf16x8 pB = __builtin_bit_cast(bf16x8, pw);
#pragma unroll
            for (int jd = 0; jd < 4; jd++)
                oacc[jd] = __builtin_amdgcn_mfma_f32_16x16x32_bf16(vf[jd], pB,
                                                                   oacc[jd], 0, 0, 0);
        }
        // explicit drain: stage(kt+1) landed + all LDS reads complete, THEN barrier
        asm volatile("s_waitcnt vmcnt(0) lgkmcnt(0)" ::: "memory");
        __builtin_amdgcn_sched_barrier(0);
        __syncthreads();
        cur ^= 1;
    }

    const float inv = 1.0f / (l_r + 1e-20f);
    us* zp = Z + (size_t)(b * 2048 + qrow) * 1024 + h * 64 + lg * 4;
#pragma unroll
    for (int jd = 0; jd < 4; jd++) {
        us4 pk;
        pk.x = f2bf(oacc[jd][0] * inv);
        pk.y = f2bf(oacc[jd][1] * inv);
        pk.z = f2bf(oacc[jd][2] * inv);
        pk.w = f2bf(oacc[jd][3] * inv);
        *(us4*)(zp + jd * 16) = pk;
    }
}

// ---------------- launcher ----------------

extern "C" void kernel_launch(void* const* d_in, const int* in_sizes, int n_in,
                              void* d_out, int out_size, void* d_ws, size_t ws_size,
                              hipStream_t stream) {
    const float* x = (const float*)d_in[0];
    const int* mask = (const int*)d_in[1];
    const float* Wqkv = (const float*)d_in[2];
    const float* Wout = (const float*)d_in[3];
    const float* bout = (const float*)d_in[4];
    float* out = (float*)d_out;
    char* ws = (char*)d_ws;

    // 48 MB layout (proven)
    unsigned short* xz    = (unsigned short*)(ws);               // 8 MB (x bf16, later Z bf16)
    unsigned short* wqkvT = (unsigned short*)(ws + (8u << 20));  // 6 MB
    unsigned short* woutT = (unsigned short*)(ws + (14u << 20)); // 2 MB
    unsigned char*  m8    = (unsigned char*)(ws + (16u << 20));  // 8 MB
    unsigned short* Qb    = (unsigned short*)(ws + (24u << 20)); // 8 MB
    unsigned short* Kb    = (unsigned short*)(ws + (32u << 20)); // 8 MB
    unsigned short* VTb   = (unsigned short*)(ws + (40u << 20)); // 8 MB

    prep<<<12288, 256, 0, stream>>>(x, xz, mask, (unsigned int*)m8);
    transposew2<<<dim3(128, 32), 256, 0, stream>>>(Wqkv, wqkvT, Wout, woutT);
    gemm_bf16<0><<<dim3(3072 / 128, 4096 / 128), 256, 0, stream>>>(
        xz, wqkvT, 4096, 3072, 1024, Qb, Kb, VTb, nullptr, nullptr);
    flash_attn<<<dim3(16, 32), 512, 0, stream>>>(Qb, Kb, VTb, m8, xz);
    gemm_bf16<1><<<dim3(1024 / 128, 4096 / 128), 256, 0, stream>>>(
        xz, woutT, 4096, 1024, 1024, nullptr, nullptr, nullptr, bout, out);
}